// Round 5
// baseline (4378.095 us; speedup 1.0000x reference)
//
#include <hip/hip_runtime.h>

#define NB 512
#define NT 256
#define NI 32
#define NH 128
#define NG 512

__device__ __forceinline__ float fsig(float x) { return 1.0f / (1.0f + __expf(-x)); }
__device__ __forceinline__ float ftanh(float x) {
    float ax = fabsf(x);
    float e  = __expf(-2.0f * ax);
    float t  = (1.0f - e) / (1.0f + e);
    return copysignf(t, x);
}

// ---------------------------------------------------------------------------
// LSTM recurrence. 256 blocks x 512 threads; block owns batches {blk, blk+256}.
// thread = gate row g (0..511). Weight row w[g][0:K] (K=160 for L0 = [h|x],
// K=128 for L1) split: k<96 in 24 float4 REGISTERS, k>=96 in LDS quads
// Q[q][g*4] (quad-major: lane g reads 16B at bank 4g%32 -> conflict-spread).
// No cross-lane reduction needed (full row per thread). h double-buffered in
// LDS (broadcast reads, free). 2 barriers/step (act handoff, h handoff).
//
// __launch_bounds__(512, 2): VERIFIED (R1) to grant exactly 128 VGPRs.
// Demand ~115 (96 weight + ~19 working) -> no spill. The R2-R4 1024-thread
// design was hard-capped at 2048/16=128 total and collapsed to 64+scratch,
// re-streaming all 320KB of weights every step (FETCH 75MB = 256x320KB).
// ---------------------------------------------------------------------------
template<bool LAYER0>
__global__ __launch_bounds__(512, 2)
void recur(const float* __restrict__ xin,   // L0: x [NB][NT][NI]; L1: xg [NB][Tc][NG]
           const float* __restrict__ w_hh,  // [NG][NH]
           const float* __restrict__ w_ih,  // L0 only [NG][NI]
           const float* __restrict__ b_ih,  // L0 only
           const float* __restrict__ b_hh,  // L0 only
           float* __restrict__ hout,        // L0: [NB][Tc][NH]; L1: unused
           float* __restrict__ h_state, float* __restrict__ c_state, // [NB][NH]
           int t0, int Tc, int first)
{
    constexpr int KQ = LAYER0 ? 16 : 8;    // LDS weight quads per gate row
    __shared__ float Q[KQ][NG * 4];        // 128KB (L0) / 64KB (L1)
    __shared__ float hx[2][2][160];        // [buf][bb][h(128)|x(32)]
    __shared__ float act[2][NG];

    const int tid = threadIdx.x;
    const int g   = tid;                   // gate row
    const int blk = blockIdx.x;
    const int ttype = g >> 7;              // 0:i 1:f 2:g 3:o

    // ---- register weights: w[g][0:96] ----
    float4 wr[24];
    {
        const float4* wrow = (const float4*)(w_hh + (size_t)g * NH);
#pragma unroll
        for (int q = 0; q < 24; ++q) wr[q] = wrow[q];
    }
    // ---- LDS weights: w[g][96:96+4*KQ] ----
#pragma unroll
    for (int q = 0; q < KQ; ++q) {
        float4 v;
        if (LAYER0 && q >= 8) v = *(const float4*)(w_ih + (size_t)g * NI + 4 * (q - 8));
        else                  v = *(const float4*)(w_hh + (size_t)g * NH + 96 + 4 * q);
        *(float4*)&Q[q][g * 4] = v;
    }

    float bias = 0.f;
    if (LAYER0) bias = b_ih[g] + b_hh[g];

    // update-role state (threads 0..255: bb=tid>>7, j=tid&127)
    const int ubb = tid >> 7, uj = tid & 127;
    float c = 0.f, hk = 0.f;
    if (tid < 256) {
        float h = 0.f;
        if (!first) {
            h  = h_state[(size_t)(blk + ubb * 256) * NH + uj];
            c  = c_state[(size_t)(blk + ubb * 256) * NH + uj];
        }
        hx[0][ubb][uj] = h;
        hk = h;
    }
    if (LAYER0 && tid < 64) {
        int bb = tid >> 5, i = tid & 31;
        hx[0][bb][128 + i] = xin[((size_t)(blk + bb * 256) * NT + t0) * NI + i];
    }
    __syncthreads();   // Q staged + h/x staged

    const size_t xgb0 = LAYER0 ? 0 : ((size_t)blk * Tc) * NG + g;
    const size_t xgb1 = LAYER0 ? 0 : ((size_t)(blk + 256) * Tc) * NG + g;

    for (int tl = 0; tl < Tc; ++tl) {
        const int buf = tl & 1, nbuf = buf ^ 1;

        // prefetch (consumed after the dot)
        float xpre = 0.f, xg0 = 0.f, xg1 = 0.f;
        if (LAYER0) {
            if (tid < 64) {
                int bb = tid >> 5, i = tid & 31;
                int tn = t0 + tl + 1; if (tn > NT - 1) tn = NT - 1;
                xpre = xin[((size_t)(blk + bb * 256) * NT + tn) * NI + i];
            }
        } else {
            xg0 = xin[xgb0 + (size_t)tl * NG];
            xg1 = xin[xgb1 + (size_t)tl * NG];
        }

        // dot: register part (quads 0..23) + LDS part (quads 24..24+KQ-1)
        float pa0 = 0.f, pb0 = 0.f, pa1 = 0.f, pb1 = 0.f;
        const float4* h0 = (const float4*)hx[buf][0];
        const float4* h1 = (const float4*)hx[buf][1];
#pragma unroll
        for (int q = 0; q < 24; ++q) {
            float4 w = wr[q], a = h0[q], b = h1[q];
            pa0 += w.x * a.x + w.y * a.y;  pb0 += w.z * a.z + w.w * a.w;
            pa1 += w.x * b.x + w.y * b.y;  pb1 += w.z * b.z + w.w * b.w;
        }
#pragma unroll
        for (int q = 0; q < KQ; ++q) {
            float4 w = *(const float4*)&Q[q][g * 4];
            float4 a = h0[24 + q], b = h1[24 + q];
            pa0 += w.x * a.x + w.y * a.y;  pb0 += w.z * a.z + w.w * a.w;
            pa1 += w.x * b.x + w.y * b.y;  pb1 += w.z * b.z + w.w * b.w;
        }
        float p0 = pa0 + pb0, p1 = pa1 + pb1;
        if (LAYER0) { p0 += bias; p1 += bias; }
        else        { p0 += xg0;  p1 += xg1;  }
        act[0][g] = (ttype == 2) ? ftanh(p0) : fsig(p0);
        act[1][g] = (ttype == 2) ? ftanh(p1) : fsig(p1);
        __syncthreads();   // act ready

        if (tid < 256) {
            float gi = act[ubb][uj];
            float gf = act[ubb][uj + 128];
            float gg = act[ubb][uj + 256];
            float go = act[ubb][uj + 384];
            c = gf * c + gi * gg;
            float hn = go * ftanh(c);
            hx[nbuf][ubb][uj] = hn;
            hk = hn;
            if (LAYER0)
                hout[((size_t)(blk + ubb * 256) * Tc + tl) * NH + uj] = hn;
        }
        if (LAYER0 && tid < 64) {
            int bb = tid >> 5, i = tid & 31;
            hx[nbuf][bb][128 + i] = xpre;
        }
        __syncthreads();   // h(nbuf) ready; act WAR-safe
    }

    if (tid < 256) {
        h_state[(size_t)(blk + ubb * 256) * NH + uj] = hk;
        c_state[(size_t)(blk + ubb * 256) * NH + uj] = c;
    }
}

// ---------------------------------------------------------------------------
// xg1 = h0 @ w_ih1^T + (b_ih1 + b_hh1)
// A [M][128], Bw [512][128], C [M][512]. 128x128 tile, 8x8 micro.
// Micro-kernel uses explicit float4 member ops ONLY (no pointer-indexed
// register arrays -> no risk of the array being demoted to scratch).
// ---------------------------------------------------------------------------
__device__ __forceinline__ void fma4(float4& acc, float a, const float4& b) {
    acc.x += a * b.x; acc.y += a * b.y; acc.z += a * b.z; acc.w += a * b.w;
}

__global__ __launch_bounds__(256, 4)
void gemm_xg(const float* __restrict__ A,
             const float* __restrict__ Bw,
             const float* __restrict__ bi, const float* __restrict__ bh,
             float* __restrict__ C, int M)
{
    __shared__ float As[32][132];
    __shared__ float Bs[32][132];
    const int tid = threadIdx.x;
    const int m0 = blockIdx.x * 128;
    const int n0 = blockIdx.y * 128;
    const int tx = tid & 15, ty = tid >> 4;

    float4 acc00[4] = {}; float4 acc01[4] = {};
    float4 acc10[4] = {}; float4 acc11[4] = {};

    for (int kp = 0; kp < 4; ++kp) {
        if (kp) __syncthreads();
#pragma unroll
        for (int r = 0; r < 4; ++r) {
            int lin = tid + 256 * r;
            int row = lin >> 3, q = lin & 7;
            float4 va = *(const float4*)&A [(size_t)(m0 + row) * 128 + kp * 32 + q * 4];
            float4 vb = *(const float4*)&Bw[(size_t)(n0 + row) * 128 + kp * 32 + q * 4];
            int k = q * 4;
            As[k + 0][row] = va.x; As[k + 1][row] = va.y;
            As[k + 2][row] = va.z; As[k + 3][row] = va.w;
            Bs[k + 0][row] = vb.x; Bs[k + 1][row] = vb.y;
            Bs[k + 2][row] = vb.z; Bs[k + 3][row] = vb.w;
        }
        __syncthreads();
#pragma unroll
        for (int k = 0; k < 32; ++k) {
            float4 a0 = *(const float4*)&As[k][ty * 4];
            float4 a1 = *(const float4*)&As[k][64 + ty * 4];
            float4 b0 = *(const float4*)&Bs[k][tx * 4];
            float4 b1 = *(const float4*)&Bs[k][64 + tx * 4];
            fma4(acc00[0], a0.x, b0); fma4(acc00[1], a0.y, b0);
            fma4(acc00[2], a0.z, b0); fma4(acc00[3], a0.w, b0);
            fma4(acc01[0], a0.x, b1); fma4(acc01[1], a0.y, b1);
            fma4(acc01[2], a0.z, b1); fma4(acc01[3], a0.w, b1);
            fma4(acc10[0], a1.x, b0); fma4(acc10[1], a1.y, b0);
            fma4(acc10[2], a1.z, b0); fma4(acc10[3], a1.w, b0);
            fma4(acc11[0], a1.x, b1); fma4(acc11[1], a1.y, b1);
            fma4(acc11[2], a1.z, b1); fma4(acc11[3], a1.w, b1);
        }
    }

    int nA = n0 + tx * 4;
    int nB = nA + 64;
    float4 biasA, biasB;
    biasA.x = bi[nA + 0] + bh[nA + 0]; biasA.y = bi[nA + 1] + bh[nA + 1];
    biasA.z = bi[nA + 2] + bh[nA + 2]; biasA.w = bi[nA + 3] + bh[nA + 3];
    biasB.x = bi[nB + 0] + bh[nB + 0]; biasB.y = bi[nB + 1] + bh[nB + 1];
    biasB.z = bi[nB + 2] + bh[nB + 2]; biasB.w = bi[nB + 3] + bh[nB + 3];
#pragma unroll
    for (int i = 0; i < 4; ++i) {
        int mA = m0 + ty * 4 + i;
        int mB = mA + 64;
        float4 o;
        o.x = acc00[i].x + biasA.x; o.y = acc00[i].y + biasA.y;
        o.z = acc00[i].z + biasA.z; o.w = acc00[i].w + biasA.w;
        *(float4*)&C[(size_t)mA * NG + nA] = o;
        o.x = acc01[i].x + biasB.x; o.y = acc01[i].y + biasB.y;
        o.z = acc01[i].z + biasB.z; o.w = acc01[i].w + biasB.w;
        *(float4*)&C[(size_t)mA * NG + nB] = o;
        o.x = acc10[i].x + biasA.x; o.y = acc10[i].y + biasA.y;
        o.z = acc10[i].z + biasA.z; o.w = acc10[i].w + biasA.w;
        *(float4*)&C[(size_t)mB * NG + nA] = o;
        o.x = acc11[i].x + biasB.x; o.y = acc11[i].y + biasB.y;
        o.z = acc11[i].z + biasB.z; o.w = acc11[i].w + biasB.w;
        *(float4*)&C[(size_t)mB * NG + nB] = o;
    }
}

// ---------------------------------------------------------------------------
// out[b] = fc2_w . relu(fc1_w @ h1_last[b] + fc1_b) + fc2_b
// ---------------------------------------------------------------------------
__global__ void fc_head(const float* __restrict__ h1,
                        const float* __restrict__ fc1w, const float* __restrict__ fc1b,
                        const float* __restrict__ fc2w, const float* __restrict__ fc2b,
                        float* __restrict__ out)
{
    int b = blockIdx.x, j = threadIdx.x;
    const float4* wr = (const float4*)(fc1w + (size_t)j * NH);
    const float4* hv = (const float4*)(h1 + (size_t)b * NH);
    float acc = fc1b[j];
#pragma unroll
    for (int q = 0; q < 32; ++q) {
        float4 w = wr[q], h = hv[q];
        acc += w.x * h.x + w.y * h.y + w.z * h.z + w.w * h.w;
    }
    float z = fmaxf(acc, 0.0f);
    float p = fc2w[j] * z;
#pragma unroll
    for (int off = 32; off > 0; off >>= 1) p += __shfl_down(p, off);
    if (j == 0) out[b] = p + fc2b[0];
}

extern "C" void kernel_launch(void* const* d_in, const int* in_sizes, int n_in,
                              void* d_out, int out_size, void* d_ws, size_t ws_size,
                              hipStream_t stream)
{
    const float* x     = (const float*)d_in[0];
    const float* w_ih0 = (const float*)d_in[1];
    const float* w_hh0 = (const float*)d_in[2];
    const float* b_ih0 = (const float*)d_in[3];
    const float* b_hh0 = (const float*)d_in[4];
    const float* w_ih1 = (const float*)d_in[5];
    const float* w_hh1 = (const float*)d_in[6];
    const float* b_ih1 = (const float*)d_in[7];
    const float* b_hh1 = (const float*)d_in[8];
    const float* fc1w  = (const float*)d_in[9];
    const float* fc1b  = (const float*)d_in[10];
    const float* fc2w  = (const float*)d_in[11];
    const float* fc2b  = (const float*)d_in[12];
    float* out = (float*)d_out;
    float* ws  = (float*)d_ws;

    // largest power-of-2 chunk whose buffers fit the workspace
    int Tc = 1;
    for (int cand = 256; cand >= 1; cand >>= 1) {
        size_t need = 4ull * ((size_t)NB * cand * (NH + NG) + 4ull * NB * NH);
        if (need <= ws_size) { Tc = cand; break; }
    }

    size_t o_h0  = 0;
    size_t o_xg  = o_h0 + (size_t)NB * Tc * NH;
    size_t o_h0s = o_xg + (size_t)NB * Tc * NG;
    size_t o_c0s = o_h0s + (size_t)NB * NH;
    size_t o_h1s = o_c0s + (size_t)NB * NH;
    size_t o_c1s = o_h1s + (size_t)NB * NH;

    const int M = NB * Tc;
    const int nchunk = NT / Tc;
    for (int c = 0; c < nchunk; ++c) {
        recur<true><<<256, 512, 0, stream>>>(x, w_hh0, w_ih0, b_ih0, b_hh0,
                                             ws + o_h0, ws + o_h0s, ws + o_c0s,
                                             c * Tc, Tc, c == 0);
        gemm_xg<<<dim3(M / 128, 4), 256, 0, stream>>>(ws + o_h0, w_ih1,
                                                      b_ih1, b_hh1,
                                                      ws + o_xg, M);
        recur<false><<<256, 512, 0, stream>>>(ws + o_xg, w_hh1, nullptr,
                                              nullptr, nullptr,
                                              nullptr, ws + o_h1s, ws + o_c1s,
                                              0, Tc, c == 0);
    }
    fc_head<<<NB, 64, 0, stream>>>(ws + o_h1s, fc1w, fc1b, fc2w, fc2b, out);
}

// Round 6
// 4187.254 us; speedup vs baseline: 1.0456x; 1.0456x over previous
//
#include <hip/hip_runtime.h>

#define NB 512
#define NT 256
#define NI 32
#define NH 128
#define NG 512

__device__ __forceinline__ float fsig(float x) { return 1.0f / (1.0f + __expf(-x)); }
__device__ __forceinline__ float ftanh(float x) {
    float ax = fabsf(x);
    float e  = __expf(-2.0f * ax);
    float t  = (1.0f - e) / (1.0f + e);
    return copysignf(t, x);
}

// ---------------------------------------------------------------------------
// LSTM recurrence. 256 blocks x 512 threads; block owns batches {blk, blk+256}.
// thread = gate row g (0..511); full K-dot per thread (no cross-lane reduce).
// Weight row w[g][0:K] (L0: K=160 virtual [h|x]; L1: K=128) split:
//   first 4*RQ floats in REGISTERS, remaining 4*KQ floats in LDS quads
//   Q[q][g*4] (quad-major; b128 per lane, throughput-bound not conflict-bound).
// h double-buffered in LDS (same-address broadcast reads -> cheap).
//
// Register-budget ledger (R1-R5 hard lessons):
//   R5: 96 reg-weights + ~34 work = ~130 > 128 grant -> spilled quads ->
//       2.7 GB/dispatch scratch re-stream. The fix is MARGIN, not hints:
//   L0: 84 + ~32 = ~116; L1: 64 + ~32 = ~96. Both fit even a 128 grant.
//   LDS (162/138 KB) forces 1 block/CU -> 2 waves/SIMD -> natural budget 256.
// ---------------------------------------------------------------------------
template<bool LAYER0>
__global__ __launch_bounds__(512, 1)
__attribute__((amdgpu_waves_per_eu(2, 2)))
void recur(const float* __restrict__ xin,   // L0: x [NB][NT][NI]; L1: xg [NB][Tc][NG]
           const float* __restrict__ w_hh,  // [NG][NH]
           const float* __restrict__ w_ih,  // L0 only [NG][NI]
           const float* __restrict__ b_ih,  // L0 only
           const float* __restrict__ b_hh,  // L0 only
           float* __restrict__ hout,        // L0: [NB][Tc][NH]; L1: unused
           float* __restrict__ h_state, float* __restrict__ c_state, // [NB][NH]
           int t0, int Tc, int first)
{
    constexpr int RQ = LAYER0 ? 21 : 16;   // register weight quads (84 / 64 floats)
    constexpr int KQ = LAYER0 ? 19 : 16;   // LDS weight quads      (76 / 64 floats)
    __shared__ float Q[KQ][NG * 4];        // 155648 B (L0) / 131072 B (L1)
    __shared__ float hx[2][2][160];        // [buf][bb][h(128)|x(32)]  2560 B
    __shared__ float act[2][NG];           // 4096 B

    const int tid = threadIdx.x;
    const int g   = tid;                   // gate row
    const int blk = blockIdx.x;
    const int ttype = g >> 7;              // 0:i 1:f 2:g 3:o

    // ---- register weights: w[g][0 : 4*RQ) ----
    float4 wr[RQ];
    {
        const float4* wrow = (const float4*)(w_hh + (size_t)g * NH);
#pragma unroll
        for (int q = 0; q < RQ; ++q) wr[q] = wrow[q];
    }
    // ---- LDS weights: w[g][4*RQ : 4*(RQ+KQ)) ----
#pragma unroll
    for (int q = 0; q < KQ; ++q) {
        int k = 4 * (RQ + q);
        float4 v;
        if (LAYER0 && k >= NH) v = *(const float4*)(w_ih + (size_t)g * NI + (k - NH));
        else                   v = *(const float4*)(w_hh + (size_t)g * NH + k);
        *(float4*)&Q[q][g * 4] = v;
    }

    float bias = 0.f;
    if (LAYER0) bias = b_ih[g] + b_hh[g];

    // update-role state (threads 0..255: bb=tid>>7, j=tid&127)
    const int ubb = tid >> 7, uj = tid & 127;
    float c = 0.f, hk = 0.f;
    if (tid < 256) {
        float h = 0.f;
        if (!first) {
            h = h_state[(size_t)(blk + ubb * 256) * NH + uj];
            c = c_state[(size_t)(blk + ubb * 256) * NH + uj];
        }
        hx[0][ubb][uj] = h;
        hk = h;
    }
    if (LAYER0 && tid < 64) {
        int bb = tid >> 5, i = tid & 31;
        hx[0][bb][128 + i] = xin[((size_t)(blk + bb * 256) * NT + t0) * NI + i];
    }
    __syncthreads();   // Q staged + h/x staged

    const size_t xgb0 = LAYER0 ? 0 : ((size_t)blk * Tc) * NG + g;
    const size_t xgb1 = LAYER0 ? 0 : ((size_t)(blk + 256) * Tc) * NG + g;

    for (int tl = 0; tl < Tc; ++tl) {
        const int buf = tl & 1, nbuf = buf ^ 1;

        // prefetch (consumed after the dot)
        float xpre = 0.f, xg0 = 0.f, xg1 = 0.f;
        if (LAYER0) {
            if (tid < 64) {
                int bb = tid >> 5, i = tid & 31;
                int tn = t0 + tl + 1; if (tn > NT - 1) tn = NT - 1;
                xpre = xin[((size_t)(blk + bb * 256) * NT + tn) * NI + i];
            }
        } else {
            xg0 = xin[xgb0 + (size_t)tl * NG];
            xg1 = xin[xgb1 + (size_t)tl * NG];
        }

        // dot: register quads then LDS quads
        float pa0 = 0.f, pb0 = 0.f, pa1 = 0.f, pb1 = 0.f;
        const float4* h0 = (const float4*)hx[buf][0];
        const float4* h1 = (const float4*)hx[buf][1];
#pragma unroll
        for (int q = 0; q < RQ; ++q) {
            float4 w = wr[q], a = h0[q], b = h1[q];
            pa0 += w.x * a.x + w.y * a.y;  pb0 += w.z * a.z + w.w * a.w;
            pa1 += w.x * b.x + w.y * b.y;  pb1 += w.z * b.z + w.w * b.w;
        }
#pragma unroll
        for (int q = 0; q < KQ; ++q) {
            float4 w = *(const float4*)&Q[q][g * 4];
            float4 a = h0[RQ + q], b = h1[RQ + q];
            pa0 += w.x * a.x + w.y * a.y;  pb0 += w.z * a.z + w.w * a.w;
            pa1 += w.x * b.x + w.y * b.y;  pb1 += w.z * b.z + w.w * b.w;
        }
        float p0 = pa0 + pb0, p1 = pa1 + pb1;
        if (LAYER0) { p0 += bias; p1 += bias; }
        else        { p0 += xg0;  p1 += xg1;  }
        act[0][g] = (ttype == 2) ? ftanh(p0) : fsig(p0);
        act[1][g] = (ttype == 2) ? ftanh(p1) : fsig(p1);
        __syncthreads();   // act ready

        if (tid < 256) {
            float gi = act[ubb][uj];
            float gf = act[ubb][uj + 128];
            float gg = act[ubb][uj + 256];
            float go = act[ubb][uj + 384];
            c = gf * c + gi * gg;
            float hn = go * ftanh(c);
            hx[nbuf][ubb][uj] = hn;
            hk = hn;
            if (LAYER0)
                hout[((size_t)(blk + ubb * 256) * Tc + tl) * NH + uj] = hn;
        }
        if (LAYER0 && tid < 64) {
            int bb = tid >> 5, i = tid & 31;
            hx[nbuf][bb][128 + i] = xpre;
        }
        __syncthreads();   // h(nbuf) ready; act WAR-safe
    }

    if (tid < 256) {
        h_state[(size_t)(blk + ubb * 256) * NH + uj] = hk;
        c_state[(size_t)(blk + ubb * 256) * NH + uj] = c;
    }
}

// ---------------------------------------------------------------------------
// xg1 = h0 @ w_ih1^T + (b_ih1 + b_hh1)
// A [M][128], Bw [512][128], C [M][512]. 128x128 tile, 8x8 micro.
// Explicit float4 member ops only (no pointer-indexed register arrays).
// ---------------------------------------------------------------------------
__device__ __forceinline__ void fma4(float4& acc, float a, const float4& b) {
    acc.x += a * b.x; acc.y += a * b.y; acc.z += a * b.z; acc.w += a * b.w;
}

__global__ __launch_bounds__(256, 4)
void gemm_xg(const float* __restrict__ A,
             const float* __restrict__ Bw,
             const float* __restrict__ bi, const float* __restrict__ bh,
             float* __restrict__ C, int M)
{
    __shared__ float As[32][132];
    __shared__ float Bs[32][132];
    const int tid = threadIdx.x;
    const int m0 = blockIdx.y * 128;
    const int n0 = blockIdx.x * 128;   // n on x: consecutive blocks share A-tile in L2
    const int tx = tid & 15, ty = tid >> 4;

    float4 acc00[4] = {}; float4 acc01[4] = {};
    float4 acc10[4] = {}; float4 acc11[4] = {};

    for (int kp = 0; kp < 4; ++kp) {
        if (kp) __syncthreads();
#pragma unroll
        for (int r = 0; r < 4; ++r) {
            int lin = tid + 256 * r;
            int row = lin >> 3, q = lin & 7;
            float4 va = *(const float4*)&A [(size_t)(m0 + row) * 128 + kp * 32 + q * 4];
            float4 vb = *(const float4*)&Bw[(size_t)(n0 + row) * 128 + kp * 32 + q * 4];
            int k = q * 4;
            As[k + 0][row] = va.x; As[k + 1][row] = va.y;
            As[k + 2][row] = va.z; As[k + 3][row] = va.w;
            Bs[k + 0][row] = vb.x; Bs[k + 1][row] = vb.y;
            Bs[k + 2][row] = vb.z; Bs[k + 3][row] = vb.w;
        }
        __syncthreads();
#pragma unroll
        for (int k = 0; k < 32; ++k) {
            float4 a0 = *(const float4*)&As[k][ty * 4];
            float4 a1 = *(const float4*)&As[k][64 + ty * 4];
            float4 b0 = *(const float4*)&Bs[k][tx * 4];
            float4 b1 = *(const float4*)&Bs[k][64 + tx * 4];
            fma4(acc00[0], a0.x, b0); fma4(acc00[1], a0.y, b0);
            fma4(acc00[2], a0.z, b0); fma4(acc00[3], a0.w, b0);
            fma4(acc01[0], a0.x, b1); fma4(acc01[1], a0.y, b1);
            fma4(acc01[2], a0.z, b1); fma4(acc01[3], a0.w, b1);
            fma4(acc10[0], a1.x, b0); fma4(acc10[1], a1.y, b0);
            fma4(acc10[2], a1.z, b0); fma4(acc10[3], a1.w, b0);
            fma4(acc11[0], a1.x, b1); fma4(acc11[1], a1.y, b1);
            fma4(acc11[2], a1.z, b1); fma4(acc11[3], a1.w, b1);
        }
    }

    int nA = n0 + tx * 4;
    int nB = nA + 64;
    float4 biasA, biasB;
    biasA.x = bi[nA + 0] + bh[nA + 0]; biasA.y = bi[nA + 1] + bh[nA + 1];
    biasA.z = bi[nA + 2] + bh[nA + 2]; biasA.w = bi[nA + 3] + bh[nA + 3];
    biasB.x = bi[nB + 0] + bh[nB + 0]; biasB.y = bi[nB + 1] + bh[nB + 1];
    biasB.z = bi[nB + 2] + bh[nB + 2]; biasB.w = bi[nB + 3] + bh[nB + 3];
#pragma unroll
    for (int i = 0; i < 4; ++i) {
        int mA = m0 + ty * 4 + i;
        int mB = mA + 64;
        float4 o;
        o.x = acc00[i].x + biasA.x; o.y = acc00[i].y + biasA.y;
        o.z = acc00[i].z + biasA.z; o.w = acc00[i].w + biasA.w;
        *(float4*)&C[(size_t)mA * NG + nA] = o;
        o.x = acc01[i].x + biasB.x; o.y = acc01[i].y + biasB.y;
        o.z = acc01[i].z + biasB.z; o.w = acc01[i].w + biasB.w;
        *(float4*)&C[(size_t)mA * NG + nB] = o;
        o.x = acc10[i].x + biasA.x; o.y = acc10[i].y + biasA.y;
        o.z = acc10[i].z + biasA.z; o.w = acc10[i].w + biasA.w;
        *(float4*)&C[(size_t)mB * NG + nA] = o;
        o.x = acc11[i].x + biasB.x; o.y = acc11[i].y + biasB.y;
        o.z = acc11[i].z + biasB.z; o.w = acc11[i].w + biasB.w;
        *(float4*)&C[(size_t)mB * NG + nB] = o;
    }
}

// ---------------------------------------------------------------------------
// out[b] = fc2_w . relu(fc1_w @ h1_last[b] + fc1_b) + fc2_b
// ---------------------------------------------------------------------------
__global__ void fc_head(const float* __restrict__ h1,
                        const float* __restrict__ fc1w, const float* __restrict__ fc1b,
                        const float* __restrict__ fc2w, const float* __restrict__ fc2b,
                        float* __restrict__ out)
{
    int b = blockIdx.x, j = threadIdx.x;
    const float4* wr = (const float4*)(fc1w + (size_t)j * NH);
    const float4* hv = (const float4*)(h1 + (size_t)b * NH);
    float acc = fc1b[j];
#pragma unroll
    for (int q = 0; q < 32; ++q) {
        float4 w = wr[q], h = hv[q];
        acc += w.x * h.x + w.y * h.y + w.z * h.z + w.w * h.w;
    }
    float z = fmaxf(acc, 0.0f);
    float p = fc2w[j] * z;
#pragma unroll
    for (int off = 32; off > 0; off >>= 1) p += __shfl_down(p, off);
    if (j == 0) out[b] = p + fc2b[0];
}

extern "C" void kernel_launch(void* const* d_in, const int* in_sizes, int n_in,
                              void* d_out, int out_size, void* d_ws, size_t ws_size,
                              hipStream_t stream)
{
    const float* x     = (const float*)d_in[0];
    const float* w_ih0 = (const float*)d_in[1];
    const float* w_hh0 = (const float*)d_in[2];
    const float* b_ih0 = (const float*)d_in[3];
    const float* b_hh0 = (const float*)d_in[4];
    const float* w_ih1 = (const float*)d_in[5];
    const float* w_hh1 = (const float*)d_in[6];
    const float* b_ih1 = (const float*)d_in[7];
    const float* b_hh1 = (const float*)d_in[8];
    const float* fc1w  = (const float*)d_in[9];
    const float* fc1b  = (const float*)d_in[10];
    const float* fc2w  = (const float*)d_in[11];
    const float* fc2b  = (const float*)d_in[12];
    float* out = (float*)d_out;
    float* ws  = (float*)d_ws;

    // largest power-of-2 chunk whose buffers fit the workspace
    int Tc = 1;
    for (int cand = 256; cand >= 1; cand >>= 1) {
        size_t need = 4ull * ((size_t)NB * cand * (NH + NG) + 4ull * NB * NH);
        if (need <= ws_size) { Tc = cand; break; }
    }

    size_t o_h0  = 0;
    size_t o_xg  = o_h0 + (size_t)NB * Tc * NH;
    size_t o_h0s = o_xg + (size_t)NB * Tc * NG;
    size_t o_c0s = o_h0s + (size_t)NB * NH;
    size_t o_h1s = o_c0s + (size_t)NB * NH;
    size_t o_c1s = o_h1s + (size_t)NB * NH;

    const int M = NB * Tc;
    const int nchunk = NT / Tc;
    for (int c = 0; c < nchunk; ++c) {
        recur<true><<<256, 512, 0, stream>>>(x, w_hh0, w_ih0, b_ih0, b_hh0,
                                             ws + o_h0, ws + o_h0s, ws + o_c0s,
                                             c * Tc, Tc, c == 0);
        gemm_xg<<<dim3(4, M / 128), 256, 0, stream>>>(ws + o_h0, w_ih1,
                                                      b_ih1, b_hh1,
                                                      ws + o_xg, M);
        recur<false><<<256, 512, 0, stream>>>(ws + o_xg, w_hh1, nullptr,
                                              nullptr, nullptr,
                                              nullptr, ws + o_h1s, ws + o_c1s,
                                              0, Tc, c == 0);
    }
    fc_head<<<NB, 64, 0, stream>>>(ws + o_h1s, fc1w, fc1b, fc2w, fc2b, out);
}

// Round 7
// 1628.639 us; speedup vs baseline: 2.6882x; 2.5710x over previous
//
#include <hip/hip_runtime.h>

#define NB 512
#define NT 256
#define NI 32
#define NH 128
#define NG 512

__device__ __forceinline__ float fsig(float x) { return 1.0f / (1.0f + __expf(-x)); }
__device__ __forceinline__ float ftanh(float x) {
    float ax = fabsf(x);
    float e  = __expf(-2.0f * ax);
    float t  = (1.0f - e) / (1.0f + e);
    return copysignf(t, x);
}

// ---------------------------------------------------------------------------
// LSTM recurrence, BOTH layers identical now: gates = xg[b,t,:] + h @ w_hh^T.
// (L0's x-projection+biases precomputed by gemm_xg<1,true> -> same shape as L1.)
// 256 blocks x 512 threads; block owns batches {blk, blk+256}.
// thread = gate row g; K=128 split: k<64 in 16 float4 REGISTERS (64 VGPRs),
// k>=64 in 16 LDS quads Q[q][g*4] (131 KB). Demand ~108 < the 128-VGPR grant
// this toolchain reliably gives at 512 threads (R1-R6 ledger: requests for
// >128 are never honored; >70 persistent weight regs always spilled).
// sched_barrier(0) fences every 4 quads bound in-flight b128 h-loads.
// ---------------------------------------------------------------------------
template<bool WRITE_H>
__global__ __launch_bounds__(512, 1)
void recur(const float* __restrict__ xg,    // [NB][Tc][NG] (bias folded in)
           const float* __restrict__ w_hh,  // [NG][NH]
           float* __restrict__ hout,        // WRITE_H: [NB][Tc][NH]
           float* __restrict__ h_state, float* __restrict__ c_state, // [NB][NH]
           int Tc, int first)
{
    __shared__ float Q[16][NG * 4];        // 131072 B
    __shared__ float hx[2][2][NH];         // 2048 B
    __shared__ float act[2][NG];           // 4096 B

    const int tid = threadIdx.x;
    const int g   = tid;
    const int blk = blockIdx.x;
    const int ttype = g >> 7;              // 0:i 1:f 2:g 3:o

    // register weights: w[g][0:64)
    float4 w0, w1, w2, w3, w4, w5, w6, w7, w8, w9, wA, wB, wC, wD, wE, wF;
    {
        const float4* wrow = (const float4*)(w_hh + (size_t)g * NH);
        w0 = wrow[0];  w1 = wrow[1];  w2 = wrow[2];  w3 = wrow[3];
        w4 = wrow[4];  w5 = wrow[5];  w6 = wrow[6];  w7 = wrow[7];
        w8 = wrow[8];  w9 = wrow[9];  wA = wrow[10]; wB = wrow[11];
        wC = wrow[12]; wD = wrow[13]; wE = wrow[14]; wF = wrow[15];
        // LDS weights: w[g][64:128)
#pragma unroll
        for (int q = 0; q < 16; ++q)
            *(float4*)&Q[q][g * 4] = wrow[16 + q];
    }

    const int ubb = tid >> 7, uj = tid & 127;   // update role (tid<256)
    float c = 0.f, hk = 0.f;
    if (tid < 256) {
        float h = 0.f;
        if (!first) {
            h = h_state[(size_t)(blk + ubb * 256) * NH + uj];
            c = c_state[(size_t)(blk + ubb * 256) * NH + uj];
        }
        hx[0][ubb][uj] = h;
        hk = h;
    }
    __syncthreads();

    const size_t xgb0 = ((size_t)blk * Tc) * NG + g;
    const size_t xgb1 = ((size_t)(blk + 256) * Tc) * NG + g;

    for (int tl = 0; tl < Tc; ++tl) {
        const int buf = tl & 1, nbuf = buf ^ 1;

        float xg0 = xg[xgb0 + (size_t)tl * NG];
        float xg1 = xg[xgb1 + (size_t)tl * NG];

        const float4* h0 = (const float4*)hx[buf][0];
        const float4* h1 = (const float4*)hx[buf][1];
        float p0 = 0.f, p1 = 0.f;

#define DOT_R(W, Qi)                                                          \
        {   float4 a = h0[Qi], b = h1[Qi];                                    \
            p0 += W.x * a.x + W.y * a.y + W.z * a.z + W.w * a.w;              \
            p1 += W.x * b.x + W.y * b.y + W.z * b.z + W.w * b.w;   }
        DOT_R(w0, 0)  DOT_R(w1, 1)  DOT_R(w2, 2)  DOT_R(w3, 3)
        __builtin_amdgcn_sched_barrier(0);
        DOT_R(w4, 4)  DOT_R(w5, 5)  DOT_R(w6, 6)  DOT_R(w7, 7)
        __builtin_amdgcn_sched_barrier(0);
        DOT_R(w8, 8)  DOT_R(w9, 9)  DOT_R(wA, 10) DOT_R(wB, 11)
        __builtin_amdgcn_sched_barrier(0);
        DOT_R(wC, 12) DOT_R(wD, 13) DOT_R(wE, 14) DOT_R(wF, 15)
        __builtin_amdgcn_sched_barrier(0);
#undef DOT_R
#pragma unroll 4
        for (int q = 0; q < 16; ++q) {
            float4 w = *(const float4*)&Q[q][g * 4];
            float4 a = h0[16 + q], b = h1[16 + q];
            p0 += w.x * a.x + w.y * a.y + w.z * a.z + w.w * a.w;
            p1 += w.x * b.x + w.y * b.y + w.z * b.z + w.w * b.w;
        }

        p0 += xg0; p1 += xg1;
        act[0][g] = (ttype == 2) ? ftanh(p0) : fsig(p0);
        act[1][g] = (ttype == 2) ? ftanh(p1) : fsig(p1);
        __syncthreads();   // act ready

        if (tid < 256) {
            float gi = act[ubb][uj];
            float gf = act[ubb][uj + 128];
            float gg = act[ubb][uj + 256];
            float go = act[ubb][uj + 384];
            c = gf * c + gi * gg;
            float hn = go * ftanh(c);
            hx[nbuf][ubb][uj] = hn;
            hk = hn;
            if (WRITE_H)
                hout[((size_t)(blk + ubb * 256) * Tc + tl) * NH + uj] = hn;
        }
        __syncthreads();   // h(nbuf) ready; act WAR-safe
    }

    if (tid < 256) {
        h_state[(size_t)(blk + ubb * 256) * NH + uj] = hk;
        c_state[(size_t)(blk + ubb * 256) * NH + uj] = c;
    }
}

// ---------------------------------------------------------------------------
// xg = A @ Bw^T + (bi + bh).  C [M][512].  K = KP*32.
// SLICED=true: A rows are x[b][t0+tl][0:32] (b = m>>tcShift, tl = m&(Tc-1)),
// else A is contiguous [M][K]. 128x128 tile, 8x8 micro, explicit float4 FMAs.
// ---------------------------------------------------------------------------
__device__ __forceinline__ void fma4(float4& acc, float a, const float4& b) {
    acc.x += a * b.x; acc.y += a * b.y; acc.z += a * b.z; acc.w += a * b.w;
}

template<int KP, bool SLICED>
__global__ __launch_bounds__(256)
void gemm_xg(const float* __restrict__ A,
             const float* __restrict__ Bw,
             const float* __restrict__ bi, const float* __restrict__ bh,
             float* __restrict__ C, int t0, int tcShift)
{
    constexpr int K = KP * 32;
    __shared__ float As[32][132];
    __shared__ float Bs[32][132];
    const int tid = threadIdx.x;
    const int n0 = blockIdx.x * 128;
    const int m0 = blockIdx.y * 128;
    const int tx = tid & 15, ty = tid >> 4;

    float4 acc00[4] = {}; float4 acc01[4] = {};
    float4 acc10[4] = {}; float4 acc11[4] = {};

    for (int kp = 0; kp < KP; ++kp) {
        if (kp) __syncthreads();
#pragma unroll
        for (int r = 0; r < 4; ++r) {
            int lin = tid + 256 * r;
            int row = lin >> 3, q = lin & 7;
            int m = m0 + row;
            size_t abase;
            if (SLICED) {
                int b = m >> tcShift, tl = m - (b << tcShift);
                abase = ((size_t)b * NT + t0 + tl) * K;
            } else {
                abase = (size_t)m * K;
            }
            float4 va = *(const float4*)&A [abase + kp * 32 + q * 4];
            float4 vb = *(const float4*)&Bw[(size_t)(n0 + row) * K + kp * 32 + q * 4];
            int k = q * 4;
            As[k + 0][row] = va.x; As[k + 1][row] = va.y;
            As[k + 2][row] = va.z; As[k + 3][row] = va.w;
            Bs[k + 0][row] = vb.x; Bs[k + 1][row] = vb.y;
            Bs[k + 2][row] = vb.z; Bs[k + 3][row] = vb.w;
        }
        __syncthreads();
#pragma unroll
        for (int k = 0; k < 32; ++k) {
            float4 a0 = *(const float4*)&As[k][ty * 4];
            float4 a1 = *(const float4*)&As[k][64 + ty * 4];
            float4 b0 = *(const float4*)&Bs[k][tx * 4];
            float4 b1 = *(const float4*)&Bs[k][64 + tx * 4];
            fma4(acc00[0], a0.x, b0); fma4(acc00[1], a0.y, b0);
            fma4(acc00[2], a0.z, b0); fma4(acc00[3], a0.w, b0);
            fma4(acc01[0], a0.x, b1); fma4(acc01[1], a0.y, b1);
            fma4(acc01[2], a0.z, b1); fma4(acc01[3], a0.w, b1);
            fma4(acc10[0], a1.x, b0); fma4(acc10[1], a1.y, b0);
            fma4(acc10[2], a1.z, b0); fma4(acc10[3], a1.w, b0);
            fma4(acc11[0], a1.x, b1); fma4(acc11[1], a1.y, b1);
            fma4(acc11[2], a1.z, b1); fma4(acc11[3], a1.w, b1);
        }
    }

    int nA = n0 + tx * 4;
    int nB = nA + 64;
    float4 biasA, biasB;
    biasA.x = bi[nA + 0] + bh[nA + 0]; biasA.y = bi[nA + 1] + bh[nA + 1];
    biasA.z = bi[nA + 2] + bh[nA + 2]; biasA.w = bi[nA + 3] + bh[nA + 3];
    biasB.x = bi[nB + 0] + bh[nB + 0]; biasB.y = bi[nB + 1] + bh[nB + 1];
    biasB.z = bi[nB + 2] + bh[nB + 2]; biasB.w = bi[nB + 3] + bh[nB + 3];
#pragma unroll
    for (int i = 0; i < 4; ++i) {
        int mA = m0 + ty * 4 + i;
        int mB = mA + 64;
        float4 o;
        o.x = acc00[i].x + biasA.x; o.y = acc00[i].y + biasA.y;
        o.z = acc00[i].z + biasA.z; o.w = acc00[i].w + biasA.w;
        *(float4*)&C[(size_t)mA * NG + nA] = o;
        o.x = acc01[i].x + biasB.x; o.y = acc01[i].y + biasB.y;
        o.z = acc01[i].z + biasB.z; o.w = acc01[i].w + biasB.w;
        *(float4*)&C[(size_t)mA * NG + nB] = o;
        o.x = acc10[i].x + biasA.x; o.y = acc10[i].y + biasA.y;
        o.z = acc10[i].z + biasA.z; o.w = acc10[i].w + biasA.w;
        *(float4*)&C[(size_t)mB * NG + nA] = o;
        o.x = acc11[i].x + biasB.x; o.y = acc11[i].y + biasB.y;
        o.z = acc11[i].z + biasB.z; o.w = acc11[i].w + biasB.w;
        *(float4*)&C[(size_t)mB * NG + nB] = o;
    }
}

// ---------------------------------------------------------------------------
// out[b] = fc2_w . relu(fc1_w @ h1_last[b] + fc1_b) + fc2_b
// ---------------------------------------------------------------------------
__global__ void fc_head(const float* __restrict__ h1,
                        const float* __restrict__ fc1w, const float* __restrict__ fc1b,
                        const float* __restrict__ fc2w, const float* __restrict__ fc2b,
                        float* __restrict__ out)
{
    int b = blockIdx.x, j = threadIdx.x;
    const float4* wr = (const float4*)(fc1w + (size_t)j * NH);
    const float4* hv = (const float4*)(h1 + (size_t)b * NH);
    float acc = fc1b[j];
#pragma unroll
    for (int q = 0; q < 32; ++q) {
        float4 w = wr[q], h = hv[q];
        acc += w.x * h.x + w.y * h.y + w.z * h.z + w.w * h.w;
    }
    float z = fmaxf(acc, 0.0f);
    float p = fc2w[j] * z;
#pragma unroll
    for (int off = 32; off > 0; off >>= 1) p += __shfl_down(p, off);
    if (j == 0) out[b] = p + fc2b[0];
}

extern "C" void kernel_launch(void* const* d_in, const int* in_sizes, int n_in,
                              void* d_out, int out_size, void* d_ws, size_t ws_size,
                              hipStream_t stream)
{
    const float* x     = (const float*)d_in[0];
    const float* w_ih0 = (const float*)d_in[1];
    const float* w_hh0 = (const float*)d_in[2];
    const float* b_ih0 = (const float*)d_in[3];
    const float* b_hh0 = (const float*)d_in[4];
    const float* w_ih1 = (const float*)d_in[5];
    const float* w_hh1 = (const float*)d_in[6];
    const float* b_ih1 = (const float*)d_in[7];
    const float* b_hh1 = (const float*)d_in[8];
    const float* fc1w  = (const float*)d_in[9];
    const float* fc1b  = (const float*)d_in[10];
    const float* fc2w  = (const float*)d_in[11];
    const float* fc2b  = (const float*)d_in[12];
    float* out = (float*)d_out;
    float* ws  = (float*)d_ws;

    // largest power-of-2 chunk whose buffers fit:
    // xg0 [NB][Tc][NG] + h0 [NB][Tc][NH] + xg1 [NB][Tc][NG] + 4 state arrays
    int Tc = 1;
    for (int cand = 256; cand >= 1; cand >>= 1) {
        size_t need = 4ull * ((size_t)NB * cand * (2 * NG + NH) + 4ull * NB * NH);
        if (need <= ws_size) { Tc = cand; break; }
    }
    int tcShift = __builtin_ctz(Tc);

    size_t o_xg0 = 0;
    size_t o_h0  = o_xg0 + (size_t)NB * Tc * NG;
    size_t o_xg1 = o_h0  + (size_t)NB * Tc * NH;
    size_t o_h0s = o_xg1 + (size_t)NB * Tc * NG;
    size_t o_c0s = o_h0s + (size_t)NB * NH;
    size_t o_h1s = o_c0s + (size_t)NB * NH;
    size_t o_c1s = o_h1s + (size_t)NB * NH;

    const int M = NB * Tc;
    const int nchunk = NT / Tc;
    for (int c = 0; c < nchunk; ++c) {
        gemm_xg<1, true><<<dim3(4, M / 128), 256, 0, stream>>>(
            x, w_ih0, b_ih0, b_hh0, ws + o_xg0, c * Tc, tcShift);
        recur<true><<<256, 512, 0, stream>>>(
            ws + o_xg0, w_hh0, ws + o_h0, ws + o_h0s, ws + o_c0s, Tc, c == 0);
        gemm_xg<4, false><<<dim3(4, M / 128), 256, 0, stream>>>(
            ws + o_h0, w_ih1, b_ih1, b_hh1, ws + o_xg1, 0, 0);
        recur<false><<<256, 512, 0, stream>>>(
            ws + o_xg1, w_hh1, nullptr, ws + o_h1s, ws + o_c1s, Tc, c == 0);
    }
    fc_head<<<NB, 64, 0, stream>>>(ws + o_h1s, fc1w, fc1b, fc2w, fc2b, out);
}

// Round 8
// 1499.532 us; speedup vs baseline: 2.9196x; 1.0861x over previous
//
#include <hip/hip_runtime.h>

#define NB 512
#define NT 256
#define NI 32
#define NH 128
#define NG 512

typedef __attribute__((ext_vector_type(8))) short bf16x8;
typedef __attribute__((ext_vector_type(4))) float f32x4;

__device__ __forceinline__ float fsig(float x) { return 1.0f / (1.0f + __expf(-x)); }
__device__ __forceinline__ float ftanh(float x) {
    float ax = fabsf(x);
    float e  = __expf(-2.0f * ax);
    float t  = (1.0f - e) / (1.0f + e);
    return copysignf(t, x);
}

// ---------------------------------------------------------------------------
// LSTM recurrence (UNCHANGED from R7 — first spill-free config; VGPR=104).
// gates = xg[b,t,:] + h @ w_hh^T for both layers; thread = gate row g;
// K=128: 16 quads in regs, 16 quads in LDS; h double-buffered in LDS.
// ---------------------------------------------------------------------------
template<bool WRITE_H>
__global__ __launch_bounds__(512, 1)
void recur(const float* __restrict__ xg,    // [NB][Tc][NG] (bias folded in)
           const float* __restrict__ w_hh,  // [NG][NH]
           float* __restrict__ hout,        // WRITE_H: [NB][Tc][NH]
           float* __restrict__ h_state, float* __restrict__ c_state, // [NB][NH]
           int Tc, int first)
{
    __shared__ float Q[16][NG * 4];        // 131072 B
    __shared__ float hx[2][2][NH];
    __shared__ float act[2][NG];

    const int tid = threadIdx.x;
    const int g   = tid;
    const int blk = blockIdx.x;
    const int ttype = g >> 7;

    float4 w0, w1, w2, w3, w4, w5, w6, w7, w8, w9, wA, wB, wC, wD, wE, wF;
    {
        const float4* wrow = (const float4*)(w_hh + (size_t)g * NH);
        w0 = wrow[0];  w1 = wrow[1];  w2 = wrow[2];  w3 = wrow[3];
        w4 = wrow[4];  w5 = wrow[5];  w6 = wrow[6];  w7 = wrow[7];
        w8 = wrow[8];  w9 = wrow[9];  wA = wrow[10]; wB = wrow[11];
        wC = wrow[12]; wD = wrow[13]; wE = wrow[14]; wF = wrow[15];
#pragma unroll
        for (int q = 0; q < 16; ++q)
            *(float4*)&Q[q][g * 4] = wrow[16 + q];
    }

    const int ubb = tid >> 7, uj = tid & 127;
    float c = 0.f, hk = 0.f;
    if (tid < 256) {
        float h = 0.f;
        if (!first) {
            h = h_state[(size_t)(blk + ubb * 256) * NH + uj];
            c = c_state[(size_t)(blk + ubb * 256) * NH + uj];
        }
        hx[0][ubb][uj] = h;
        hk = h;
    }
    __syncthreads();

    const size_t xgb0 = ((size_t)blk * Tc) * NG + g;
    const size_t xgb1 = ((size_t)(blk + 256) * Tc) * NG + g;

    for (int tl = 0; tl < Tc; ++tl) {
        const int buf = tl & 1, nbuf = buf ^ 1;

        float xg0 = xg[xgb0 + (size_t)tl * NG];
        float xg1 = xg[xgb1 + (size_t)tl * NG];

        const float4* h0 = (const float4*)hx[buf][0];
        const float4* h1 = (const float4*)hx[buf][1];
        float p0 = 0.f, p1 = 0.f;

#define DOT_R(W, Qi)                                                          \
        {   float4 a = h0[Qi], b = h1[Qi];                                    \
            p0 += W.x * a.x + W.y * a.y + W.z * a.z + W.w * a.w;              \
            p1 += W.x * b.x + W.y * b.y + W.z * b.z + W.w * b.w;   }
        DOT_R(w0, 0)  DOT_R(w1, 1)  DOT_R(w2, 2)  DOT_R(w3, 3)
        __builtin_amdgcn_sched_barrier(0);
        DOT_R(w4, 4)  DOT_R(w5, 5)  DOT_R(w6, 6)  DOT_R(w7, 7)
        __builtin_amdgcn_sched_barrier(0);
        DOT_R(w8, 8)  DOT_R(w9, 9)  DOT_R(wA, 10) DOT_R(wB, 11)
        __builtin_amdgcn_sched_barrier(0);
        DOT_R(wC, 12) DOT_R(wD, 13) DOT_R(wE, 14) DOT_R(wF, 15)
        __builtin_amdgcn_sched_barrier(0);
#undef DOT_R
#pragma unroll 4
        for (int q = 0; q < 16; ++q) {
            float4 w = *(const float4*)&Q[q][g * 4];
            float4 a = h0[16 + q], b = h1[16 + q];
            p0 += w.x * a.x + w.y * a.y + w.z * a.z + w.w * a.w;
            p1 += w.x * b.x + w.y * b.y + w.z * b.z + w.w * b.w;
        }

        p0 += xg0; p1 += xg1;
        act[0][g] = (ttype == 2) ? ftanh(p0) : fsig(p0);
        act[1][g] = (ttype == 2) ? ftanh(p1) : fsig(p1);
        __syncthreads();

        if (tid < 256) {
            float gi = act[ubb][uj];
            float gf = act[ubb][uj + 128];
            float gg = act[ubb][uj + 256];
            float go = act[ubb][uj + 384];
            c = gf * c + gi * gg;
            float hn = go * ftanh(c);
            hx[nbuf][ubb][uj] = hn;
            hk = hn;
            if (WRITE_H)
                hout[((size_t)(blk + ubb * 256) * Tc + tl) * NH + uj] = hn;
        }
        __syncthreads();
    }

    if (tid < 256) {
        h_state[(size_t)(blk + ubb * 256) * NH + uj] = hk;
        c_state[(size_t)(blk + ubb * 256) * NH + uj] = c;
    }
}

// ---------------------------------------------------------------------------
// Split-bf16 MFMA GEMM: C[M][512] = A[M][K] @ Bw[512][K]^T + (bi+bh).
// a = a_hi + a_lo, w = w_hi + w_lo (bf16 RNE); keep hi*hi + hi*lo + lo*hi
// -> rel err ~2^-17, exact-fp32-like for this use. mfma_f32_16x16x32_bf16.
// Verified layouts (m89/m120): A-op [m=lane&15][k=quad*8+j] (k-contig row),
// B-op [n=lane&15][k=quad*8+j], C/D row=quad*4+reg, col=lane&15.
// Block 256 thr: tile M=128 (wave w -> m-tiles 2w,2w+1), N=64 (4 n-tiles),
// K staged per 32. SLICED: A row m is x[b][t0+tl][0:K], b=m>>tcShift.
// ---------------------------------------------------------------------------
__device__ __forceinline__ unsigned short f2bf_rne(float f) {
    unsigned u = __float_as_uint(f);
    return (unsigned short)((u + 0x7FFFu + ((u >> 16) & 1u)) >> 16);
}
__device__ __forceinline__ void split2(float a, float b, unsigned& hi, unsigned& lo) {
    unsigned short ha = f2bf_rne(a), hb = f2bf_rne(b);
    float ra = a - __uint_as_float((unsigned)ha << 16);
    float rb = b - __uint_as_float((unsigned)hb << 16);
    hi = (unsigned)ha | ((unsigned)f2bf_rne(b) << 16);
    lo = (unsigned)f2bf_rne(ra) | ((unsigned)f2bf_rne(rb) << 16);
    (void)hb;
}
#define MFMA16(accv, av, bv) \
    accv = __builtin_amdgcn_mfma_f32_16x16x32_bf16(av, bv, accv, 0, 0, 0)

template<int KP, bool SLICED>
__global__ __launch_bounds__(256)
void gemm_mfma(const float* __restrict__ A,
               const float* __restrict__ Bw,
               const float* __restrict__ bi, const float* __restrict__ bh,
               float* __restrict__ C, int t0, int tcShift)
{
    constexpr int K = KP * 32;
    __shared__ __align__(16) unsigned short Ah[4][128][8], Al[4][128][8]; // 8KB ea
    __shared__ __align__(16) unsigned short Bh[4][64][8],  Bl[4][64][8];  // 4KB ea
    const int tid  = threadIdx.x;
    const int n0   = blockIdx.x * 64;
    const int m0   = blockIdx.y * 128;
    const int wv   = tid >> 6;
    const int lane = tid & 63;
    const int quad = lane >> 4, ml = lane & 15;

    f32x4 acc[2][4] = {};
    float bias[4];
#pragma unroll
    for (int nt = 0; nt < 4; ++nt) {
        int n = n0 + nt * 16 + ml;
        bias[nt] = bi[n] + bh[n];
    }

    for (int kp = 0; kp < KP; ++kp) {
        if (kp) __syncthreads();
        // ---- stage A (2 units/thread): unit=(m, k-chunk c) ----
#pragma unroll
        for (int r = 0; r < 2; ++r) {
            int u = tid + 256 * r;
            int m = u >> 2, ck = u & 3;
            size_t abase;
            if (SLICED) {
                int mg = m0 + m;
                int b  = mg >> tcShift, tl = mg & ((1 << tcShift) - 1);
                abase = ((size_t)b * NT + (t0 + tl)) * K;
            } else {
                abase = (size_t)(m0 + m) * K;
            }
            const float* s = A + abase + kp * 32 + ck * 8;
            float4 v0 = *(const float4*)s;
            float4 v1 = *(const float4*)(s + 4);
            uint4 H, L;
            split2(v0.x, v0.y, H.x, L.x); split2(v0.z, v0.w, H.y, L.y);
            split2(v1.x, v1.y, H.z, L.z); split2(v1.z, v1.w, H.w, L.w);
            *(uint4*)&Ah[ck][m][0] = H;
            *(uint4*)&Al[ck][m][0] = L;
        }
        // ---- stage B (1 unit/thread) ----
        {
            int n = tid >> 2, ck = tid & 3;
            const float* s = Bw + (size_t)(n0 + n) * K + kp * 32 + ck * 8;
            float4 v0 = *(const float4*)s;
            float4 v1 = *(const float4*)(s + 4);
            uint4 H, L;
            split2(v0.x, v0.y, H.x, L.x); split2(v0.z, v0.w, H.y, L.y);
            split2(v1.x, v1.y, H.z, L.z); split2(v1.z, v1.w, H.w, L.w);
            *(uint4*)&Bh[ck][n][0] = H;
            *(uint4*)&Bl[ck][n][0] = L;
        }
        __syncthreads();

        // ---- MFMA: wave wv owns m-tiles {2wv, 2wv+1} x 4 n-tiles ----
        bf16x8 ah0 = *(const bf16x8*)&Ah[quad][(2 * wv + 0) * 16 + ml][0];
        bf16x8 al0 = *(const bf16x8*)&Al[quad][(2 * wv + 0) * 16 + ml][0];
        bf16x8 ah1 = *(const bf16x8*)&Ah[quad][(2 * wv + 1) * 16 + ml][0];
        bf16x8 al1 = *(const bf16x8*)&Al[quad][(2 * wv + 1) * 16 + ml][0];
#pragma unroll
        for (int nt = 0; nt < 4; ++nt) {
            bf16x8 bhv = *(const bf16x8*)&Bh[quad][nt * 16 + ml][0];
            bf16x8 blv = *(const bf16x8*)&Bl[quad][nt * 16 + ml][0];
            MFMA16(acc[0][nt], ah0, bhv);
            MFMA16(acc[0][nt], ah0, blv);
            MFMA16(acc[0][nt], al0, bhv);
            MFMA16(acc[1][nt], ah1, bhv);
            MFMA16(acc[1][nt], ah1, blv);
            MFMA16(acc[1][nt], al1, bhv);
        }
    }

    // ---- epilogue: D row = quad*4+reg, col = ml ----
#pragma unroll
    for (int mt = 0; mt < 2; ++mt)
#pragma unroll
        for (int nt = 0; nt < 4; ++nt)
#pragma unroll
            for (int reg = 0; reg < 4; ++reg) {
                int m = m0 + (2 * wv + mt) * 16 + quad * 4 + reg;
                int n = n0 + nt * 16 + ml;
                C[(size_t)m * NG + n] = acc[mt][nt][reg] + bias[nt];
            }
}

// ---------------------------------------------------------------------------
// out[b] = fc2_w . relu(fc1_w @ h1_last[b] + fc1_b) + fc2_b
// ---------------------------------------------------------------------------
__global__ void fc_head(const float* __restrict__ h1,
                        const float* __restrict__ fc1w, const float* __restrict__ fc1b,
                        const float* __restrict__ fc2w, const float* __restrict__ fc2b,
                        float* __restrict__ out)
{
    int b = blockIdx.x, j = threadIdx.x;
    const float4* wr = (const float4*)(fc1w + (size_t)j * NH);
    const float4* hv = (const float4*)(h1 + (size_t)b * NH);
    float acc = fc1b[j];
#pragma unroll
    for (int q = 0; q < 32; ++q) {
        float4 w = wr[q], h = hv[q];
        acc += w.x * h.x + w.y * h.y + w.z * h.z + w.w * h.w;
    }
    float z = fmaxf(acc, 0.0f);
    float p = fc2w[j] * z;
#pragma unroll
    for (int off = 32; off > 0; off >>= 1) p += __shfl_down(p, off);
    if (j == 0) out[b] = p + fc2b[0];
}

extern "C" void kernel_launch(void* const* d_in, const int* in_sizes, int n_in,
                              void* d_out, int out_size, void* d_ws, size_t ws_size,
                              hipStream_t stream)
{
    const float* x     = (const float*)d_in[0];
    const float* w_ih0 = (const float*)d_in[1];
    const float* w_hh0 = (const float*)d_in[2];
    const float* b_ih0 = (const float*)d_in[3];
    const float* b_hh0 = (const float*)d_in[4];
    const float* w_ih1 = (const float*)d_in[5];
    const float* w_hh1 = (const float*)d_in[6];
    const float* b_ih1 = (const float*)d_in[7];
    const float* b_hh1 = (const float*)d_in[8];
    const float* fc1w  = (const float*)d_in[9];
    const float* fc1b  = (const float*)d_in[10];
    const float* fc2w  = (const float*)d_in[11];
    const float* fc2b  = (const float*)d_in[12];
    float* out = (float*)d_out;
    float* ws  = (float*)d_ws;

    // xg buffer reused for layers 0 and 1 (xg0 dead after recur<true>):
    // xg [NB][Tc][NG] + h0 [NB][Tc][NH] + 4 state arrays
    int Tc = 1;
    for (int cand = 256; cand >= 1; cand >>= 1) {
        size_t need = 4ull * ((size_t)NB * cand * (NG + NH) + 4ull * NB * NH);
        if (need <= ws_size) { Tc = cand; break; }
    }
    int tcShift = __builtin_ctz((unsigned)Tc);

    size_t o_xg  = 0;
    size_t o_h0  = o_xg  + (size_t)NB * Tc * NG;
    size_t o_h0s = o_h0  + (size_t)NB * Tc * NH;
    size_t o_c0s = o_h0s + (size_t)NB * NH;
    size_t o_h1s = o_c0s + (size_t)NB * NH;
    size_t o_c1s = o_h1s + (size_t)NB * NH;

    const int M = NB * Tc;
    const int nchunk = NT / Tc;
    for (int c = 0; c < nchunk; ++c) {
        gemm_mfma<1, true><<<dim3(8, M / 128), 256, 0, stream>>>(
            x, w_ih0, b_ih0, b_hh0, ws + o_xg, c * Tc, tcShift);
        recur<true><<<256, 512, 0, stream>>>(
            ws + o_xg, w_hh0, ws + o_h0, ws + o_h0s, ws + o_c0s, Tc, c == 0);
        gemm_mfma<4, false><<<dim3(8, M / 128), 256, 0, stream>>>(
            ws + o_h0, w_ih1, b_ih1, b_hh1, ws + o_xg, 0, 0);
        recur<false><<<256, 512, 0, stream>>>(
            ws + o_xg, w_hh1, nullptr, ws + o_h1s, ws + o_c1s, Tc, c == 0);
    }
    fc_head<<<NB, 64, 0, stream>>>(ws + o_h1s, fc1w, fc1b, fc2w, fc2b, out);
}